// Round 2
// baseline (257.472 us; speedup 1.0000x reference)
//
#include <hip/hip_runtime.h>
#include <math.h>

#define SE_B   32
#define SE_C   256
#define SE_HID 16
#define SE_HW  4096   // 64*64
#define SE_HW4 1024   // float4 per (b,c) plane

typedef float f4v __attribute__((ext_vector_type(4)));

// Kernel 1: plane means, wave-per-plane. 2048 blocks x 4 waves; each wave
// owns one (b,c) plane. 16 independent float4 loads per lane (deep MLP),
// pure shuffle reduction — no LDS, no __syncthreads (no counter drain).
// Normal (caching) loads on purpose: leaves x resident in the 256 MiB L3
// so the apply pass re-reads it without HBM traffic.
__global__ __launch_bounds__(256) void se_mean_kernel(const float* __restrict__ x,
                                                      float* __restrict__ s) {
    const int wave = threadIdx.x >> 6;
    const int lane = threadIdx.x & 63;
    const int plane = blockIdx.x * 4 + wave;   // b*C + c

    const float4* xp = (const float4*)x + (size_t)plane * SE_HW4;

    float sum = 0.f;
#pragma unroll
    for (int k = 0; k < 16; ++k) {
        float4 v = xp[lane + k * 64];
        sum += (v.x + v.y) + (v.z + v.w);
    }
#pragma unroll
    for (int off = 32; off > 0; off >>= 1) sum += __shfl_down(sum, off, 64);

    if (lane == 0) s[plane] = sum * (1.0f / SE_HW);
}

// Kernel 2: gate MLP, once per batch (32 blocks total).
// h_i = relu(b1_i + sum_c s[b,c]*w1[i,c]);  g_c = sigmoid(b2_c + sum_i h_i*w2[c,i])
__global__ __launch_bounds__(256) void se_gate_kernel(const float* __restrict__ s,
                                                      const float* __restrict__ w1,
                                                      const float* __restrict__ b1,
                                                      const float* __restrict__ w2,
                                                      const float* __restrict__ b2,
                                                      float* __restrict__ g) {
    const int b = blockIdx.x;      // batch
    const int tid = threadIdx.x;   // also the output channel c

    __shared__ float s_sh[SE_C];
    __shared__ float part[16][17];   // [chunk j][hidden i], +1 col padding
    __shared__ float h_sh[SE_HID];

    s_sh[tid] = s[b * SE_C + tid];
    __syncthreads();

    // Stage 1: partial dot products. thread (i = tid&15 hidden, j = tid>>4 chunk)
    const int i = tid & 15;
    const int j = tid >> 4;
    {
        const float* wrow = w1 + i * SE_C + j * 16;
        const float* srow = s_sh + j * 16;
        float p = 0.f;
#pragma unroll
        for (int k = 0; k < 16; ++k) p = fmaf(srow[k], wrow[k], p);
        part[j][i] = p;
    }
    __syncthreads();

    // Stage 2: column-sum -> h
    if (tid < SE_HID) {
        float acc = b1[tid];
#pragma unroll
        for (int k = 0; k < 16; ++k) acc += part[k][tid];
        h_sh[tid] = fmaxf(acc, 0.f);
    }
    __syncthreads();

    // Stage 3: every thread computes one channel's gate
    {
        float acc = b2[tid];
        const float* w2r = w2 + tid * SE_HID;
#pragma unroll
        for (int k = 0; k < 16; ++k) acc = fmaf(h_sh[k], w2r[k], acc);
        g[b * SE_C + tid] = 1.0f / (1.0f + expf(-acc));
    }
}

// Kernel 3: streaming scale, wave-per-plane. No LDS, no barriers.
// All 16 float4 loads issued before any store (max read MLP, x comes
// from L3). NT stores keep the 128 MiB of output from evicting x in L3.
__global__ __launch_bounds__(256) void se_apply_kernel(const float* __restrict__ x,
                                                       const float* __restrict__ g,
                                                       float* __restrict__ out) {
    const int wave = threadIdx.x >> 6;
    const int lane = threadIdx.x & 63;
    const int plane = blockIdx.x * 4 + wave;

    const float gv = g[plane];   // wave-uniform
    const float4* xp = (const float4*)x + (size_t)plane * SE_HW4;
    float4* op = (float4*)out + (size_t)plane * SE_HW4;

    float4 v[16];
#pragma unroll
    for (int k = 0; k < 16; ++k) v[k] = xp[lane + k * 64];

#pragma unroll
    for (int k = 0; k < 16; ++k) {
        v[k].x *= gv; v[k].y *= gv; v[k].z *= gv; v[k].w *= gv;
        __builtin_nontemporal_store(*(f4v*)&v[k], (f4v*)(op + lane + k * 64));
    }
}

extern "C" void kernel_launch(void* const* d_in, const int* in_sizes, int n_in,
                              void* d_out, int out_size, void* d_ws, size_t ws_size,
                              hipStream_t stream) {
    const float* x  = (const float*)d_in[0];
    const float* w1 = (const float*)d_in[1];
    const float* b1 = (const float*)d_in[2];
    const float* w2 = (const float*)d_in[3];
    const float* b2 = (const float*)d_in[4];
    float* out = (float*)d_out;

    float* s = (float*)d_ws;               // [B*C] plane means
    float* g = (float*)d_ws + SE_B * SE_C; // [B*C] gates

    se_mean_kernel<<<SE_B * SE_C / 4, 256, 0, stream>>>(x, s);
    se_gate_kernel<<<SE_B, 256, 0, stream>>>(s, w1, b1, w2, b2, g);
    se_apply_kernel<<<SE_B * SE_C / 4, 256, 0, stream>>>(x, g, out);
}

// Round 3
// 257.435 us; speedup vs baseline: 1.0001x; 1.0001x over previous
//
#include <hip/hip_runtime.h>
#include <math.h>

#define SE_B   32
#define SE_C   256
#define SE_HID 16
#define SE_HW  4096   // 64*64
#define SE_HW4 1024   // float4 per (b,c) plane

typedef float f4v __attribute__((ext_vector_type(4)));

// Kernel 1: plane means, wave-per-plane. 2048 blocks x 4 waves; each wave
// owns one (b,c) plane. 16 independent float4 loads per lane, 4 parallel
// accumulator chains (accuracy + ILP), pure shuffle reduction — no LDS,
// no __syncthreads. Caching loads on purpose: leaves x resident in the
// 256 MiB L3 so the apply pass re-reads it without HBM traffic.
__global__ __launch_bounds__(256) void se_mean_kernel(const float* __restrict__ x,
                                                      float* __restrict__ s) {
    const int wave = threadIdx.x >> 6;
    const int lane = threadIdx.x & 63;
    const int plane = blockIdx.x * 4 + wave;   // b*C + c

    const float4* xp = (const float4*)x + (size_t)plane * SE_HW4;

    float4 acc = {0.f, 0.f, 0.f, 0.f};
#pragma unroll
    for (int k = 0; k < 16; ++k) {
        float4 v = xp[lane + k * 64];
        acc.x += v.x; acc.y += v.y; acc.z += v.z; acc.w += v.w;
    }
    float sum = (acc.x + acc.y) + (acc.z + acc.w);
#pragma unroll
    for (int off = 32; off > 0; off >>= 1) sum += __shfl_down(sum, off, 64);

    if (lane == 0) s[plane] = sum * (1.0f / SE_HW);
}

// Kernel 2: fused gate + scale, wave-per-plane, ZERO barriers / ZERO LDS.
// Each wave computes its own channel's gate with shuffles only:
//   lane (i = lane&15 hidden, j = lane>>4 chunk-of-64-channels)
//   p = sum_k s[b, j*64+k] * w1[i, j*64+k]          (64 FMA/lane)
//   h_i = relu(b1_i + shfl_xor-sum over j)          (2 shuffles)
//   g   = sigmoid(b2_c + shfl_xor-sum_i h_i*w2[c,i]) (4 shuffles)
// w1 (16 KB) is L1-resident; s row is L1/L2. No s_barrier -> no forced
// vmcnt(0) drains. NT stores keep output from evicting x in L3.
__global__ __launch_bounds__(256) void se_gate_apply_kernel(const float* __restrict__ x,
                                                            const float* __restrict__ s,
                                                            const float* __restrict__ w1,
                                                            const float* __restrict__ b1,
                                                            const float* __restrict__ w2,
                                                            const float* __restrict__ b2,
                                                            float* __restrict__ out) {
    const int wave = threadIdx.x >> 6;
    const int lane = threadIdx.x & 63;
    const int plane = blockIdx.x * 4 + wave;
    const int b = plane >> 8;    // batch
    const int c = plane & 255;   // channel

    const int i = lane & 15;     // hidden unit
    const int j = lane >> 4;     // chunk of 64 channels

    // Layer 1 partial dot product over this lane's 64 channels.
    const float4* srow = (const float4*)(s + b * SE_C) + j * 16;
    const float4* wrow = (const float4*)(w1 + i * SE_C) + j * 16;
    float p = 0.f;
#pragma unroll
    for (int k = 0; k < 16; ++k) {
        float4 sv = srow[k];
        float4 wv = wrow[k];
        p = fmaf(sv.x, wv.x, p);
        p = fmaf(sv.y, wv.y, p);
        p = fmaf(sv.z, wv.z, p);
        p = fmaf(sv.w, wv.w, p);
    }
    // Sum the 4 chunks (j lives in lane bits 4-5).
    p += __shfl_xor(p, 16, 64);
    p += __shfl_xor(p, 32, 64);
    const float h = fmaxf(p + b1[i], 0.f);

    // Layer 2: every 16-lane group holds the full h vector (one h_i per lane).
    float t = h * w2[c * SE_HID + i];
#pragma unroll
    for (int off = 8; off > 0; off >>= 1) t += __shfl_xor(t, off, 64);
    const float gv = 1.0f / (1.0f + expf(-(t + b2[c])));

    // Apply: two batches of 8 float4 (keeps VGPR < 128 -> 4 waves/SIMD).
    const float4* xp = (const float4*)x + (size_t)plane * SE_HW4;
    float4* op = (float4*)out + (size_t)plane * SE_HW4;

    float4 v[8];
#pragma unroll
    for (int k = 0; k < 8; ++k) v[k] = xp[lane + k * 64];
#pragma unroll
    for (int k = 0; k < 8; ++k) {
        v[k].x *= gv; v[k].y *= gv; v[k].z *= gv; v[k].w *= gv;
        __builtin_nontemporal_store(*(f4v*)&v[k], (f4v*)(op + lane + k * 64));
    }
#pragma unroll
    for (int k = 0; k < 8; ++k) v[k] = xp[lane + (k + 8) * 64];
#pragma unroll
    for (int k = 0; k < 8; ++k) {
        v[k].x *= gv; v[k].y *= gv; v[k].z *= gv; v[k].w *= gv;
        __builtin_nontemporal_store(*(f4v*)&v[k], (f4v*)(op + lane + (k + 8) * 64));
    }
}

extern "C" void kernel_launch(void* const* d_in, const int* in_sizes, int n_in,
                              void* d_out, int out_size, void* d_ws, size_t ws_size,
                              hipStream_t stream) {
    const float* x  = (const float*)d_in[0];
    const float* w1 = (const float*)d_in[1];
    const float* b1 = (const float*)d_in[2];
    const float* w2 = (const float*)d_in[3];
    const float* b2 = (const float*)d_in[4];
    float* out = (float*)d_out;

    float* s = (float*)d_ws;   // [B*C] plane means

    se_mean_kernel<<<SE_B * SE_C / 4, 256, 0, stream>>>(x, s);
    se_gate_apply_kernel<<<SE_B * SE_C / 4, 256, 0, stream>>>(x, s, w1, b1, w2, b2, out);
}